// Round 1
// baseline (527.002 us; speedup 1.0000x reference)
//
#include <hip/hip_runtime.h>
#include <math.h>

#define N3 262144           // 64^3
#define NPTS_PER_BLOCK 256

// ---------------------------------------------------------------------------
// Lattice helper: emb row (4) and sh1 row (3) for tap p in [0,27)
// Matches reference _lattice() in f32.
// ---------------------------------------------------------------------------
__device__ inline void lattice_row(int p, float* embr, float* sh1r) {
    int i = p / 9, j = (p / 3) % 3, k = p % 3;
    float gx = (float)(i - 1), gy = (float)(j - 1), gz = (float)(k - 1);
    float r = sqrtf(gx * gx + gy * gy + gz * gz);
    float inv = (r > 0.f) ? (1.0f / fmaxf(r, 1e-9f)) : 0.f;
    const float s3 = 1.7320508075688772f;
    sh1r[0] = s3 * gx * inv;
    sh1r[1] = s3 * gy * inv;
    sh1r[2] = s3 * gz * inv;
    const float centers[4] = {0.f, 0.33333334f, 0.6666667f, 1.f};
    const float step = 0.33333334f;
    #pragma unroll
    for (int b = 0; b < 4; b++) {
        float dd = (r - centers[b]) / step;
        float e = 0.f;
        if (fabsf(dd) < 1.f)
            e = 1.14136f * expf(2.f) * expf(-1.f / fmaxf(1.f - dd * dd, 1e-9f));
        embr[b] = e;
    }
}

__device__ inline float eps3f(int m, int s, int n) {
    if (m == s || s == n || m == n) return 0.f;
    return ((m == 0 && s == 1 && n == 2) || (m == 1 && s == 2 && n == 0) ||
            (m == 2 && s == 0 && n == 1)) ? 1.f : -1.f;
}

// ---------------------------------------------------------------------------
// Build Km1 (27,8,48) and Km2 (27,40,48) exactly as reference _kernel1/_kernel2
// ---------------------------------------------------------------------------
__global__ void build_kernels_kernel(const float* __restrict__ w1,
                                     const float* __restrict__ w2,
                                     float* __restrict__ Km1,
                                     float* __restrict__ Km2) {
    const float inv_ks15 = 0.19245008972987526f;  // 1/3^1.5
    // ---- Km1 ----
    for (int idx = threadIdx.x; idx < 27 * 8 * 48; idx += blockDim.x) {
        int p = idx / 384, rem = idx % 384, i = rem / 48, o = rem % 48;
        float embr[4], sh1r[3];
        lattice_row(p, embr, sh1r);
        const float a = 0.35355339059327373f;  // 1/sqrt(8)
        float val;
        int c;
        if (o < 16) c = i * 16 + o;
        else if (o < 24) c = 128 + i * 8 + (o - 16);
        else c = 192 + i * 8 + (o - 24) / 3;
        float W = 0.f;
        #pragma unroll
        for (int b = 0; b < 4; b++) W += embr[b] * w1[b * 256 + c];
        W *= inv_ks15;
        if (o < 24) val = a * W;
        else val = a * W * sh1r[(o - 24) % 3];
        Km1[idx] = val;
    }
    // ---- Km2 ----
    for (int idx = threadIdx.x; idx < 27 * 40 * 48; idx += blockDim.x) {
        int p = idx / 1920, rem = idx % 1920, row = rem / 48, o = rem % 48;
        float embr[4], sh1r[3];
        lattice_row(p, embr, sh1r);
        auto Wat = [&](int c) -> float {
            float s = 0.f;
            #pragma unroll
            for (int b = 0; b < 4; b++) s += embr[b] * w2[b * 832 + c];
            return s * inv_ks15;
        };
        const float a_s = 0.2041241452319315f;   // 1/sqrt(24)
        const float a_v = 0.17677669529663687f;  // 1/sqrt(32)
        const float a_s3 = 0.11785113019775793f; // a_s/sqrt(3)
        const float a_v6 = 0.07216878364870322f; // a_v/sqrt(6)
        float val;
        if (row < 16) {
            int i = row;
            if (o < 16) val = a_s * Wat(i * 16 + o);
            else if (o < 24) val = a_s * Wat(256 + i * 8 + (o - 16));
            else {
                int jj = (o - 24) / 3, mo = (o - 24) % 3;
                val = a_v * Wat(384 + i * 8 + jj) * sh1r[mo];
            }
        } else {
            int u = (row - 16) / 3, m = (row - 16) % 3;
            if (o < 16) val = a_s3 * Wat(576 + u * 16 + o) * sh1r[m];
            else if (o < 24) val = a_s3 * Wat(704 + u * 8 + (o - 16)) * sh1r[m];
            else {
                int jj = (o - 24) / 3, n = (o - 24) % 3;
                float v0 = (m == n) ? a_v * Wat(512 + u * 8 + jj) : 0.f;
                float epssum = 0.f;
                #pragma unroll
                for (int s = 0; s < 3; s++) epssum += eps3f(m, s, n) * sh1r[s];
                val = v0 + a_v6 * Wat(768 + u * 8 + jj) * epssum;
            }
        }
        Km2[idx] = val;
    }
}

// 7 nonzero taps: center p=13, faces p=4(d-1),22(d+1),10(h-1),16(h+1),12(w-1),14(w+1)
__device__ __constant__ int c_taps[7] = {13, 4, 22, 10, 16, 12, 14};

// ---------------------------------------------------------------------------
// conv1: x(8,64^3) -> ypre(48,64^3), fused sc1 skip on first 24 channels
// ---------------------------------------------------------------------------
__global__ __launch_bounds__(256) void conv1_kernel(const float* __restrict__ x,
                                                    const float* __restrict__ Km1,
                                                    const float* __restrict__ sc1,
                                                    float* __restrict__ out) {
    __shared__ float km[7 * 8 * 48];   // 10.5 KB
    __shared__ float sk[8 * 24];
    for (int t = threadIdx.x; t < 7 * 384; t += 256) {
        int tp = t / 384;
        km[t] = Km1[c_taps[tp] * 384 + (t % 384)];
    }
    for (int t = threadIdx.x; t < 192; t += 256) sk[t] = sc1[t];
    __syncthreads();

    int idx = blockIdx.x * 256 + threadIdx.x;
    int w = idx & 63, h = (idx >> 6) & 63, d = idx >> 12;

    float xc[8];
    #pragma unroll
    for (int i = 0; i < 8; i++) xc[i] = x[i * N3 + idx];

    float acc[48];
    #pragma unroll
    for (int o = 0; o < 24; o++) {
        float s = 0.f;
        #pragma unroll
        for (int i = 0; i < 8; i++) s += xc[i] * sk[i * 24 + o];
        acc[o] = 0.35355339059327373f * s;
    }
    #pragma unroll
    for (int o = 24; o < 48; o++) acc[o] = 0.f;

    // center tap
    #pragma unroll
    for (int i = 0; i < 8; i++) {
        float v = xc[i];
        const float* kr = km + i * 48;
        #pragma unroll
        for (int o = 0; o < 48; o++) acc[o] += v * kr[o];
    }
    // 6 face taps
    const int offs[6][3] = {{-1,0,0},{1,0,0},{0,-1,0},{0,1,0},{0,0,-1},{0,0,1}};
    #pragma unroll
    for (int t = 0; t < 6; t++) {
        int nd = d + offs[t][0], nh = h + offs[t][1], nw = w + offs[t][2];
        if ((unsigned)nd >= 64u || (unsigned)nh >= 64u || (unsigned)nw >= 64u) continue;
        int nidx = (nd << 12) | (nh << 6) | nw;
        const float* kmt = km + (t + 1) * 384;
        #pragma unroll
        for (int i = 0; i < 8; i++) {
            float v = x[i * N3 + nidx];
            const float* kr = kmt + i * 48;
            #pragma unroll
            for (int o = 0; o < 48; o++) acc[o] += v * kr[o];
        }
    }
    #pragma unroll
    for (int o = 0; o < 48; o++) out[o * N3 + idx] = acc[o];
}

// ---------------------------------------------------------------------------
// conv2: y(40,64^3) -> zpre(48,64^3), fused sc2_s / sc2_v skips
// ---------------------------------------------------------------------------
__global__ __launch_bounds__(256) void conv2_kernel(const float* __restrict__ y,
                                                    const float* __restrict__ Km2,
                                                    const float* __restrict__ sc2s,
                                                    const float* __restrict__ sc2v,
                                                    float* __restrict__ out) {
    __shared__ float km[7 * 40 * 48];  // 52.5 KB
    __shared__ float sks[16 * 24];
    __shared__ float skv[64];
    for (int t = threadIdx.x; t < 7 * 1920; t += 256) {
        int tp = t / 1920;
        km[t] = Km2[c_taps[tp] * 1920 + (t % 1920)];
    }
    for (int t = threadIdx.x; t < 384; t += 256) sks[t] = sc2s[t];
    if (threadIdx.x < 64) skv[threadIdx.x] = sc2v[threadIdx.x];
    __syncthreads();

    int idx = blockIdx.x * 256 + threadIdx.x;
    int w = idx & 63, h = (idx >> 6) & 63, d = idx >> 12;

    float yc[40];
    #pragma unroll
    for (int i = 0; i < 40; i++) yc[i] = y[i * N3 + idx];

    float acc[48];
    // skip: z[:24] += (y[:16] @ sc2_s)/4
    #pragma unroll
    for (int o = 0; o < 24; o++) {
        float s = 0.f;
        #pragma unroll
        for (int i = 0; i < 16; i++) s += yc[i] * sks[i * 24 + o];
        acc[o] = 0.25f * s;
    }
    // skip: z[24+j*3+m] += sum_u yv[u,m]*sc2_v[u,j] / sqrt(8)
    #pragma unroll
    for (int jj = 0; jj < 8; jj++) {
        #pragma unroll
        for (int m = 0; m < 3; m++) {
            float s = 0.f;
            #pragma unroll
            for (int u = 0; u < 8; u++) s += yc[16 + u * 3 + m] * skv[u * 8 + jj];
            acc[24 + jj * 3 + m] = 0.35355339059327373f * s;
        }
    }
    // center tap
    #pragma unroll
    for (int i = 0; i < 40; i++) {
        float v = yc[i];
        const float* kr = km + i * 48;
        #pragma unroll
        for (int o = 0; o < 48; o++) acc[o] += v * kr[o];
    }
    // 6 face taps
    const int offs[6][3] = {{-1,0,0},{1,0,0},{0,-1,0},{0,1,0},{0,0,-1},{0,0,1}};
    #pragma unroll
    for (int t = 0; t < 6; t++) {
        int nd = d + offs[t][0], nh = h + offs[t][1], nw = w + offs[t][2];
        if ((unsigned)nd >= 64u || (unsigned)nh >= 64u || (unsigned)nw >= 64u) continue;
        int nidx = (nd << 12) | (nh << 6) | nw;
        const float* kmt = km + (t + 1) * 1920;
        #pragma unroll
        for (int i = 0; i < 40; i++) {
            float v = y[i * N3 + nidx];
            const float* kr = kmt + i * 48;
            #pragma unroll
            for (int o = 0; o < 48; o++) acc[o] += v * kr[o];
        }
    }
    #pragma unroll
    for (int o = 0; o < 48; o++) out[o * N3 + idx] = acc[o];
}

// ---------------------------------------------------------------------------
// BN partial reduction: grid (8 slabs, 32 quantities)
// q<24: scalar channel q -> (sum, sumsq); q>=24: vector u=q-24 -> (0, sum|v|^2)
// ---------------------------------------------------------------------------
__global__ __launch_bounds__(256) void bn_partial_kernel(const float* __restrict__ zp,
                                                         float* __restrict__ part) {
    int q = blockIdx.y, slab = blockIdx.x;
    int base = slab * 32768;
    float s1 = 0.f, s2 = 0.f;
    if (q < 24) {
        const float4* p = (const float4*)(zp + q * N3 + base);
        for (int i = threadIdx.x; i < 8192; i += 256) {
            float4 v = p[i];
            s1 += v.x + v.y + v.z + v.w;
            s2 += v.x * v.x + v.y * v.y + v.z * v.z + v.w * v.w;
        }
    } else {
        int u = q - 24;
        for (int m = 0; m < 3; m++) {
            const float4* p = (const float4*)(zp + (24 + u * 3 + m) * N3 + base);
            for (int i = threadIdx.x; i < 8192; i += 256) {
                float4 v = p[i];
                s2 += v.x * v.x + v.y * v.y + v.z * v.z + v.w * v.w;
            }
        }
    }
    __shared__ float a1[256], a2[256];
    a1[threadIdx.x] = s1;
    a2[threadIdx.x] = s2;
    __syncthreads();
    for (int st = 128; st > 0; st >>= 1) {
        if (threadIdx.x < st) {
            a1[threadIdx.x] += a1[threadIdx.x + st];
            a2[threadIdx.x] += a2[threadIdx.x + st];
        }
        __syncthreads();
    }
    if (threadIdx.x == 0) {
        part[(q * 8 + slab) * 2] = a1[0];
        part[(q * 8 + slab) * 2 + 1] = a2[0];
    }
}

// ---------------------------------------------------------------------------
// Finalize BN stats into scale/bias: sb[0:24]=scaleS, sb[24:48]=biasS, sb[48:56]=scaleV
// ---------------------------------------------------------------------------
__global__ void finalize_kernel(const float* __restrict__ part,
                                const float* __restrict__ wsc,
                                const float* __restrict__ bsc,
                                const float* __restrict__ wvc,
                                float* __restrict__ sb) {
    int t = threadIdx.x;
    const float invN = 1.0f / 262144.0f;
    if (t < 24) {
        float s1 = 0.f, s2 = 0.f;
        for (int s = 0; s < 8; s++) {
            s1 += part[(t * 8 + s) * 2];
            s2 += part[(t * 8 + s) * 2 + 1];
        }
        float mu = s1 * invN;
        float var = s2 * invN - mu * mu;
        float inv = rsqrtf(var + 1e-5f);
        sb[t] = wsc[t] * inv;
        sb[24 + t] = bsc[t] - mu * wsc[t] * inv;
    } else if (t < 32) {
        int u = t - 24;
        float s2 = 0.f;
        for (int s = 0; s < 8; s++) s2 += part[(t * 8 + s) * 2 + 1];
        float n2 = s2 * invN;
        sb[48 + u] = wvc[u] * rsqrtf(n2 + 1e-5f);
    }
}

// ---------------------------------------------------------------------------
// BN apply + gate: zp(48ch) -> out(40ch): relu(s), v*sigmoid(g)
// ---------------------------------------------------------------------------
__global__ __launch_bounds__(256) void bn_gate_kernel(const float* __restrict__ zp,
                                                      const float* __restrict__ sb,
                                                      float* __restrict__ out) {
    int idx = blockIdx.x * 256 + threadIdx.x;
    float g[8];
    #pragma unroll
    for (int u = 0; u < 8; u++) {
        float v = zp[(16 + u) * N3 + idx] * sb[16 + u] + sb[40 + u];
        g[u] = 1.0f / (1.0f + expf(-v));
    }
    #pragma unroll
    for (int c = 0; c < 16; c++) {
        float v = zp[c * N3 + idx] * sb[c] + sb[24 + c];
        out[c * N3 + idx] = fmaxf(v, 0.f);
    }
    #pragma unroll
    for (int u = 0; u < 8; u++) {
        float sv = sb[48 + u] * g[u];
        #pragma unroll
        for (int m = 0; m < 3; m++) {
            out[(16 + u * 3 + m) * N3 + idx] = zp[(24 + u * 3 + m) * N3 + idx] * sv;
        }
    }
}

// ---------------------------------------------------------------------------
extern "C" void kernel_launch(void* const* d_in, const int* in_sizes, int n_in,
                              void* d_out, int out_size, void* d_ws, size_t ws_size,
                              hipStream_t stream) {
    const float* x      = (const float*)d_in[0];
    const float* w1     = (const float*)d_in[1];
    const float* sc1    = (const float*)d_in[2];
    const float* w2     = (const float*)d_in[3];
    const float* sc2s   = (const float*)d_in[4];
    const float* sc2v   = (const float*)d_in[5];
    const float* bn1_ws = (const float*)d_in[6];
    const float* bn1_bs = (const float*)d_in[7];
    const float* bn1_wv = (const float*)d_in[8];
    const float* bn2_ws = (const float*)d_in[9];
    const float* bn2_bs = (const float*)d_in[10];
    const float* bn2_wv = (const float*)d_in[11];
    float* out = (float*)d_out;
    char* ws = (char*)d_ws;

    float* Km1   = (float*)(ws + 0);        // 41472 B
    float* Km2   = (float*)(ws + 41472);    // 207360 B
    float* part1 = (float*)(ws + 248832);   // 2048 B
    float* sb1   = (float*)(ws + 250880);   // 256 B
    float* part2 = (float*)(ws + 251136);   // 2048 B
    float* sb2   = (float*)(ws + 253184);   // 256 B
    float* bufA  = (float*)(ws + 262144);   // 48*N3*4 = 50331648 B

    hipLaunchKernelGGL(build_kernels_kernel, dim3(1), dim3(256), 0, stream, w1, w2, Km1, Km2);
    hipLaunchKernelGGL(conv1_kernel, dim3(1024), dim3(256), 0, stream, x, Km1, sc1, bufA);
    hipLaunchKernelGGL(bn_partial_kernel, dim3(8, 32), dim3(256), 0, stream, bufA, part1);
    hipLaunchKernelGGL(finalize_kernel, dim3(1), dim3(64), 0, stream, part1, bn1_ws, bn1_bs, bn1_wv, sb1);
    hipLaunchKernelGGL(bn_gate_kernel, dim3(1024), dim3(256), 0, stream, bufA, sb1, out);
    hipLaunchKernelGGL(conv2_kernel, dim3(1024), dim3(256), 0, stream, out, Km2, sc2s, sc2v, bufA);
    hipLaunchKernelGGL(bn_partial_kernel, dim3(8, 32), dim3(256), 0, stream, bufA, part2);
    hipLaunchKernelGGL(finalize_kernel, dim3(1), dim3(64), 0, stream, part2, bn2_ws, bn2_bs, bn2_wv, sb2);
    hipLaunchKernelGGL(bn_gate_kernel, dim3(1024), dim3(256), 0, stream, bufA, sb2, out);
}

// Round 2
// 305.806 us; speedup vs baseline: 1.7233x; 1.7233x over previous
//
#include <hip/hip_runtime.h>
#include <math.h>

#define N3 262144           // 64^3

// ---------------------------------------------------------------------------
// Lattice helper: emb row (4) and sh1 row (3) for tap p in [0,27)
// Matches reference _lattice() in f32.
// ---------------------------------------------------------------------------
__device__ inline void lattice_row(int p, float* embr, float* sh1r) {
    int i = p / 9, j = (p / 3) % 3, k = p % 3;
    float gx = (float)(i - 1), gy = (float)(j - 1), gz = (float)(k - 1);
    float r = sqrtf(gx * gx + gy * gy + gz * gz);
    float inv = (r > 0.f) ? (1.0f / fmaxf(r, 1e-9f)) : 0.f;
    const float s3 = 1.7320508075688772f;
    sh1r[0] = s3 * gx * inv;
    sh1r[1] = s3 * gy * inv;
    sh1r[2] = s3 * gz * inv;
    const float centers[4] = {0.f, 0.33333334f, 0.6666667f, 1.f};
    const float step = 0.33333334f;
    #pragma unroll
    for (int b = 0; b < 4; b++) {
        float dd = (r - centers[b]) / step;
        float e = 0.f;
        if (fabsf(dd) < 1.f)
            e = 1.14136f * expf(2.f) * expf(-1.f / fmaxf(1.f - dd * dd, 1e-9f));
        embr[b] = e;
    }
}

__device__ inline float eps3f(int m, int s, int n) {
    if (m == s || s == n || m == n) return 0.f;
    return ((m == 0 && s == 1 && n == 2) || (m == 1 && s == 2 && n == 0) ||
            (m == 2 && s == 0 && n == 1)) ? 1.f : -1.f;
}

// ---------------------------------------------------------------------------
// Build Km1 (27,8,48) and Km2 (27,40,48) exactly as reference _kernel1/_kernel2
// Fully parallel: one element per thread across the grid.
// Elements 0..10367 -> Km1; 10368..62207 -> Km2.
// ---------------------------------------------------------------------------
__global__ __launch_bounds__(256) void build_kernels_kernel(
        const float* __restrict__ w1,
        const float* __restrict__ w2,
        float* __restrict__ Km1,
        float* __restrict__ Km2) {
    const float inv_ks15 = 0.19245008972987526f;  // 1/3^1.5
    int gid = blockIdx.x * 256 + threadIdx.x;
    if (gid < 27 * 8 * 48) {
        int idx = gid;
        int p = idx / 384, rem = idx % 384, i = rem / 48, o = rem % 48;
        float embr[4], sh1r[3];
        lattice_row(p, embr, sh1r);
        const float a = 0.35355339059327373f;  // 1/sqrt(8)
        float val;
        int c;
        if (o < 16) c = i * 16 + o;
        else if (o < 24) c = 128 + i * 8 + (o - 16);
        else c = 192 + i * 8 + (o - 24) / 3;
        float W = 0.f;
        #pragma unroll
        for (int b = 0; b < 4; b++) W += embr[b] * w1[b * 256 + c];
        W *= inv_ks15;
        if (o < 24) val = a * W;
        else val = a * W * sh1r[(o - 24) % 3];
        Km1[idx] = val;
    } else if (gid < 27 * 8 * 48 + 27 * 40 * 48) {
        int idx = gid - 27 * 8 * 48;
        int p = idx / 1920, rem = idx % 1920, row = rem / 48, o = rem % 48;
        float embr[4], sh1r[3];
        lattice_row(p, embr, sh1r);
        auto Wat = [&](int c) -> float {
            float s = 0.f;
            #pragma unroll
            for (int b = 0; b < 4; b++) s += embr[b] * w2[b * 832 + c];
            return s * inv_ks15;
        };
        const float a_s = 0.2041241452319315f;   // 1/sqrt(24)
        const float a_v = 0.17677669529663687f;  // 1/sqrt(32)
        const float a_s3 = 0.11785113019775793f; // a_s/sqrt(3)
        const float a_v6 = 0.07216878364870322f; // a_v/sqrt(6)
        float val;
        if (row < 16) {
            int i = row;
            if (o < 16) val = a_s * Wat(i * 16 + o);
            else if (o < 24) val = a_s * Wat(256 + i * 8 + (o - 16));
            else {
                int jj = (o - 24) / 3, mo = (o - 24) % 3;
                val = a_v * Wat(384 + i * 8 + jj) * sh1r[mo];
            }
        } else {
            int u = (row - 16) / 3, m = (row - 16) % 3;
            if (o < 16) val = a_s3 * Wat(576 + u * 16 + o) * sh1r[m];
            else if (o < 24) val = a_s3 * Wat(704 + u * 8 + (o - 16)) * sh1r[m];
            else {
                int jj = (o - 24) / 3, n = (o - 24) % 3;
                float v0 = (m == n) ? a_v * Wat(512 + u * 8 + jj) : 0.f;
                float epssum = 0.f;
                #pragma unroll
                for (int s = 0; s < 3; s++) epssum += eps3f(m, s, n) * sh1r[s];
                val = v0 + a_v6 * Wat(768 + u * 8 + jj) * epssum;
            }
        }
        Km2[idx] = val;
    }
}

// 7 nonzero taps: center p=13, faces p=4(d-1),22(d+1),10(h-1),16(h+1),12(w-1),14(w+1)
__device__ __constant__ int c_taps[7] = {13, 4, 22, 10, 16, 12, 14};

// ---------------------------------------------------------------------------
// conv1: x(8,64^3) -> ypre(48,64^3), fused sc1 skip on first 24 channels
// ---------------------------------------------------------------------------
__global__ __launch_bounds__(256) void conv1_kernel(const float* __restrict__ x,
                                                    const float* __restrict__ Km1,
                                                    const float* __restrict__ sc1,
                                                    float* __restrict__ out) {
    __shared__ float km[7 * 8 * 48];   // 10.5 KB
    __shared__ float sk[8 * 24];
    for (int t = threadIdx.x; t < 7 * 384; t += 256) {
        int tp = t / 384;
        km[t] = Km1[c_taps[tp] * 384 + (t % 384)];
    }
    for (int t = threadIdx.x; t < 192; t += 256) sk[t] = sc1[t];
    __syncthreads();

    int idx = blockIdx.x * 256 + threadIdx.x;
    int w = idx & 63, h = (idx >> 6) & 63, d = idx >> 12;

    float xc[8];
    #pragma unroll
    for (int i = 0; i < 8; i++) xc[i] = x[i * N3 + idx];

    float acc[48];
    #pragma unroll
    for (int o = 0; o < 24; o++) {
        float s = 0.f;
        #pragma unroll
        for (int i = 0; i < 8; i++) s += xc[i] * sk[i * 24 + o];
        acc[o] = 0.35355339059327373f * s;
    }
    #pragma unroll
    for (int o = 24; o < 48; o++) acc[o] = 0.f;

    // center tap
    #pragma unroll
    for (int i = 0; i < 8; i++) {
        float v = xc[i];
        const float* kr = km + i * 48;
        #pragma unroll
        for (int o = 0; o < 48; o++) acc[o] += v * kr[o];
    }
    // 6 face taps
    const int offs[6][3] = {{-1,0,0},{1,0,0},{0,-1,0},{0,1,0},{0,0,-1},{0,0,1}};
    #pragma unroll
    for (int t = 0; t < 6; t++) {
        int nd = d + offs[t][0], nh = h + offs[t][1], nw = w + offs[t][2];
        if ((unsigned)nd >= 64u || (unsigned)nh >= 64u || (unsigned)nw >= 64u) continue;
        int nidx = (nd << 12) | (nh << 6) | nw;
        const float* kmt = km + (t + 1) * 384;
        #pragma unroll
        for (int i = 0; i < 8; i++) {
            float v = x[i * N3 + nidx];
            const float* kr = kmt + i * 48;
            #pragma unroll
            for (int o = 0; o < 48; o++) acc[o] += v * kr[o];
        }
    }
    #pragma unroll
    for (int o = 0; o < 48; o++) out[o * N3 + idx] = acc[o];
}

// ---------------------------------------------------------------------------
// conv2: y(40,64^3) -> zpre(48,64^3), fused sc2_s / sc2_v skips
// ---------------------------------------------------------------------------
__global__ __launch_bounds__(256) void conv2_kernel(const float* __restrict__ y,
                                                    const float* __restrict__ Km2,
                                                    const float* __restrict__ sc2s,
                                                    const float* __restrict__ sc2v,
                                                    float* __restrict__ out) {
    __shared__ float km[7 * 40 * 48];  // 52.5 KB
    __shared__ float sks[16 * 24];
    __shared__ float skv[64];
    for (int t = threadIdx.x; t < 7 * 1920; t += 256) {
        int tp = t / 1920;
        km[t] = Km2[c_taps[tp] * 1920 + (t % 1920)];
    }
    for (int t = threadIdx.x; t < 384; t += 256) sks[t] = sc2s[t];
    if (threadIdx.x < 64) skv[threadIdx.x] = sc2v[threadIdx.x];
    __syncthreads();

    int idx = blockIdx.x * 256 + threadIdx.x;
    int w = idx & 63, h = (idx >> 6) & 63, d = idx >> 12;

    float yc[40];
    #pragma unroll
    for (int i = 0; i < 40; i++) yc[i] = y[i * N3 + idx];

    float acc[48];
    // skip: z[:24] += (y[:16] @ sc2_s)/4
    #pragma unroll
    for (int o = 0; o < 24; o++) {
        float s = 0.f;
        #pragma unroll
        for (int i = 0; i < 16; i++) s += yc[i] * sks[i * 24 + o];
        acc[o] = 0.25f * s;
    }
    // skip: z[24+j*3+m] += sum_u yv[u,m]*sc2_v[u,j] / sqrt(8)
    #pragma unroll
    for (int jj = 0; jj < 8; jj++) {
        #pragma unroll
        for (int m = 0; m < 3; m++) {
            float s = 0.f;
            #pragma unroll
            for (int u = 0; u < 8; u++) s += yc[16 + u * 3 + m] * skv[u * 8 + jj];
            acc[24 + jj * 3 + m] = 0.35355339059327373f * s;
        }
    }
    // center tap
    #pragma unroll
    for (int i = 0; i < 40; i++) {
        float v = yc[i];
        const float* kr = km + i * 48;
        #pragma unroll
        for (int o = 0; o < 48; o++) acc[o] += v * kr[o];
    }
    // 6 face taps
    const int offs[6][3] = {{-1,0,0},{1,0,0},{0,-1,0},{0,1,0},{0,0,-1},{0,0,1}};
    #pragma unroll
    for (int t = 0; t < 6; t++) {
        int nd = d + offs[t][0], nh = h + offs[t][1], nw = w + offs[t][2];
        if ((unsigned)nd >= 64u || (unsigned)nh >= 64u || (unsigned)nw >= 64u) continue;
        int nidx = (nd << 12) | (nh << 6) | nw;
        const float* kmt = km + (t + 1) * 1920;
        #pragma unroll
        for (int i = 0; i < 40; i++) {
            float v = y[i * N3 + nidx];
            const float* kr = kmt + i * 48;
            #pragma unroll
            for (int o = 0; o < 48; o++) acc[o] += v * kr[o];
        }
    }
    #pragma unroll
    for (int o = 0; o < 48; o++) out[o * N3 + idx] = acc[o];
}

// ---------------------------------------------------------------------------
// BN partial reduction: grid (8 slabs, 32 quantities)
// q<24: scalar channel q -> (sum, sumsq); q>=24: vector u=q-24 -> (0, sum|v|^2)
// ---------------------------------------------------------------------------
__global__ __launch_bounds__(256) void bn_partial_kernel(const float* __restrict__ zp,
                                                         float* __restrict__ part) {
    int q = blockIdx.y, slab = blockIdx.x;
    int base = slab * 32768;
    float s1 = 0.f, s2 = 0.f;
    if (q < 24) {
        const float4* p = (const float4*)(zp + q * N3 + base);
        for (int i = threadIdx.x; i < 8192; i += 256) {
            float4 v = p[i];
            s1 += v.x + v.y + v.z + v.w;
            s2 += v.x * v.x + v.y * v.y + v.z * v.z + v.w * v.w;
        }
    } else {
        int u = q - 24;
        for (int m = 0; m < 3; m++) {
            const float4* p = (const float4*)(zp + (24 + u * 3 + m) * N3 + base);
            for (int i = threadIdx.x; i < 8192; i += 256) {
                float4 v = p[i];
                s2 += v.x * v.x + v.y * v.y + v.z * v.z + v.w * v.w;
            }
        }
    }
    __shared__ float a1[256], a2[256];
    a1[threadIdx.x] = s1;
    a2[threadIdx.x] = s2;
    __syncthreads();
    for (int st = 128; st > 0; st >>= 1) {
        if (threadIdx.x < st) {
            a1[threadIdx.x] += a1[threadIdx.x + st];
            a2[threadIdx.x] += a2[threadIdx.x + st];
        }
        __syncthreads();
    }
    if (threadIdx.x == 0) {
        part[(q * 8 + slab) * 2] = a1[0];
        part[(q * 8 + slab) * 2 + 1] = a2[0];
    }
}

// ---------------------------------------------------------------------------
// Finalize BN stats into scale/bias: sb[0:24]=scaleS, sb[24:48]=biasS, sb[48:56]=scaleV
// ---------------------------------------------------------------------------
__global__ void finalize_kernel(const float* __restrict__ part,
                                const float* __restrict__ wsc,
                                const float* __restrict__ bsc,
                                const float* __restrict__ wvc,
                                float* __restrict__ sb) {
    int t = threadIdx.x;
    const float invN = 1.0f / 262144.0f;
    if (t < 24) {
        float s1 = 0.f, s2 = 0.f;
        for (int s = 0; s < 8; s++) {
            s1 += part[(t * 8 + s) * 2];
            s2 += part[(t * 8 + s) * 2 + 1];
        }
        float mu = s1 * invN;
        float var = s2 * invN - mu * mu;
        float inv = rsqrtf(var + 1e-5f);
        sb[t] = wsc[t] * inv;
        sb[24 + t] = bsc[t] - mu * wsc[t] * inv;
    } else if (t < 32) {
        int u = t - 24;
        float s2 = 0.f;
        for (int s = 0; s < 8; s++) s2 += part[(t * 8 + s) * 2 + 1];
        float n2 = s2 * invN;
        sb[48 + u] = wvc[u] * rsqrtf(n2 + 1e-5f);
    }
}

// ---------------------------------------------------------------------------
// BN apply + gate: zp(48ch) -> out(40ch): relu(s), v*sigmoid(g)
// ---------------------------------------------------------------------------
__global__ __launch_bounds__(256) void bn_gate_kernel(const float* __restrict__ zp,
                                                      const float* __restrict__ sb,
                                                      float* __restrict__ out) {
    int idx = blockIdx.x * 256 + threadIdx.x;
    float g[8];
    #pragma unroll
    for (int u = 0; u < 8; u++) {
        float v = zp[(16 + u) * N3 + idx] * sb[16 + u] + sb[40 + u];
        g[u] = 1.0f / (1.0f + expf(-v));
    }
    #pragma unroll
    for (int c = 0; c < 16; c++) {
        float v = zp[c * N3 + idx] * sb[c] + sb[24 + c];
        out[c * N3 + idx] = fmaxf(v, 0.f);
    }
    #pragma unroll
    for (int u = 0; u < 8; u++) {
        float sv = sb[48 + u] * g[u];
        #pragma unroll
        for (int m = 0; m < 3; m++) {
            out[(16 + u * 3 + m) * N3 + idx] = zp[(24 + u * 3 + m) * N3 + idx] * sv;
        }
    }
}

// ---------------------------------------------------------------------------
extern "C" void kernel_launch(void* const* d_in, const int* in_sizes, int n_in,
                              void* d_out, int out_size, void* d_ws, size_t ws_size,
                              hipStream_t stream) {
    const float* x      = (const float*)d_in[0];
    const float* w1     = (const float*)d_in[1];
    const float* sc1    = (const float*)d_in[2];
    const float* w2     = (const float*)d_in[3];
    const float* sc2s   = (const float*)d_in[4];
    const float* sc2v   = (const float*)d_in[5];
    const float* bn1_ws = (const float*)d_in[6];
    const float* bn1_bs = (const float*)d_in[7];
    const float* bn1_wv = (const float*)d_in[8];
    const float* bn2_ws = (const float*)d_in[9];
    const float* bn2_bs = (const float*)d_in[10];
    const float* bn2_wv = (const float*)d_in[11];
    float* out = (float*)d_out;
    char* ws = (char*)d_ws;

    float* Km1   = (float*)(ws + 0);        // 41472 B
    float* Km2   = (float*)(ws + 41472);    // 207360 B
    float* part1 = (float*)(ws + 248832);   // 2048 B
    float* sb1   = (float*)(ws + 250880);   // 256 B
    float* part2 = (float*)(ws + 251136);   // 2048 B
    float* sb2   = (float*)(ws + 253184);   // 256 B
    float* bufA  = (float*)(ws + 262144);   // 48*N3*4 = 50331648 B

    // 62208 total elements (Km1 10368 + Km2 51840), one per thread
    hipLaunchKernelGGL(build_kernels_kernel, dim3(243), dim3(256), 0, stream, w1, w2, Km1, Km2);
    hipLaunchKernelGGL(conv1_kernel, dim3(1024), dim3(256), 0, stream, x, Km1, sc1, bufA);
    hipLaunchKernelGGL(bn_partial_kernel, dim3(8, 32), dim3(256), 0, stream, bufA, part1);
    hipLaunchKernelGGL(finalize_kernel, dim3(1), dim3(64), 0, stream, part1, bn1_ws, bn1_bs, bn1_wv, sb1);
    hipLaunchKernelGGL(bn_gate_kernel, dim3(1024), dim3(256), 0, stream, bufA, sb1, out);
    hipLaunchKernelGGL(conv2_kernel, dim3(1024), dim3(256), 0, stream, out, Km2, sc2s, sc2v, bufA);
    hipLaunchKernelGGL(bn_partial_kernel, dim3(8, 32), dim3(256), 0, stream, bufA, part2);
    hipLaunchKernelGGL(finalize_kernel, dim3(1), dim3(64), 0, stream, part2, bn2_ws, bn2_bs, bn2_wv, sb2);
    hipLaunchKernelGGL(bn_gate_kernel, dim3(1024), dim3(256), 0, stream, bufA, sb2, out);
}